// Round 6
// baseline (151.984 us; speedup 1.0000x reference)
//
#include <hip/hip_runtime.h>

#define NVEC 65536   // B*H*W = 64*32*32
#define KC   1024
#define DD   64
#define NTILE 64     // n per block
#define KTILE 128    // k per LDS tile

// d_out layout (f32): [0]=loss, [1..4194305)=z_q (B,D,H,W), [4194305]=perplexity, [4194306..)=idx
#define OUT_ZQ   1
#define OUT_PPL  4194305
#define OUT_IDX  4194306

// ws layout (bytes)
#define WS_HIST  0        // int[KC]  = 4096
#define WS_SUMSQ 4096     // double   = 8
#define WS_SE    4104     // float[KC]= 4096

// prep_emb: se[k] = np.sum(emb**2, axis=1), numpy pairwise order (verified bit-exact)
__global__ __launch_bounds__(256) void prep_emb(const float* __restrict__ emb,
                                                float* __restrict__ se) {
    const int k = blockIdx.x * 256 + threadIdx.x;
    const float* er = emb + (size_t)k * 64;
    float r[8];
    #pragma unroll
    for (int c = 0; c < 64; ++c) {
        float v = er[c];
        float s = __fmul_rn(v, v);
        if (c < 8) r[c] = s;
        else       r[c & 7] = __fadd_rn(r[c & 7], s);
    }
    se[k] = __fadd_rn(__fadd_rn(__fadd_rn(r[0], r[1]), __fadd_rn(r[2], r[3])),
                      __fadd_rn(__fadd_rn(r[4], r[5]), __fadd_rn(r[6], r[7])));
}

// dist_fused: register-tiled GEMM-with-argmin + fused epilogue.
// Block = 64 n x all 1024 k -> argmin is block-final; write idx/z_q/hist/sumsq here.
// Per (n,k): sequential __fmaf_rn over c=0..63, then d = fmaf(-2,acc, fadd(sz,se))
// (bit-identical: 2*acc is exact, single rounding of s-2acc either way).
// k ascending + strict <  => numpy first-index tie-break; cross-thread merge via
// (monotone<<10 | k) atomicMin in LDS.
__global__ __launch_bounds__(256)
__attribute__((amdgpu_waves_per_eu(3)))
void dist_fused(const float* __restrict__ z,
                const float* __restrict__ emb,
                const float* __restrict__ se,
                float* __restrict__ out,
                int* __restrict__ hist,
                double* __restrict__ sumsq) {
    __shared__ float zt[64][64];               // 16 KB  [c][n]
    __shared__ float et[64][KTILE];            // 32 KB  [c][k]
    __shared__ float lds_sz[64];
    __shared__ unsigned long long red[64];

    const int tid = threadIdx.x;
    const int tn  = tid & 15;      // 4 n each
    const int tk  = tid >> 4;      // 8 k each within the 128-k tile
    const int n0  = blockIdx.x * NTILE;
    const int b   = n0 >> 10;
    const int hw0 = n0 & 1023;

    // ---- stage zt[c][nl] (z is [b][c][hw]: hw is n-contiguous, no transpose) ----
    {
        const float* zbase = z + (size_t)b * 65536 + hw0;
        #pragma unroll
        for (int j = 0; j < 4; ++j) {
            int idx = tid + j * 256;
            int c   = idx >> 4;
            int nl4 = (idx & 15) * 4;
            *(float4*)&zt[c][nl4] = *(const float4*)(zbase + (size_t)c * 1024 + nl4);
        }
        if (tid < 64) red[tid] = 0xFFFFFFFFFFFFFFFFULL;
    }

    // ---- prefetch emb tile 0 into registers (T14 issue-early) ----
    const int krow = tid >> 1;     // 0..127
    const int cq   = tid & 1;
    float4 pf[8];
    {
        const float* er = emb + (size_t)krow * 64 + cq * 4;
        #pragma unroll
        for (int q = 0; q < 8; ++q) pf[q] = *(const float4*)(er + q * 8);
    }
    __syncthreads();   // zt ready

    // ---- sz[n] from staged zt, exact numpy pairwise order (verified) ----
    if (tid < 64) {
        float r[8];
        #pragma unroll
        for (int c = 0; c < 64; ++c) {
            float v = zt[c][tid];
            float s = __fmul_rn(v, v);
            if (c < 8) r[c] = s;
            else       r[c & 7] = __fadd_rn(r[c & 7], s);
        }
        lds_sz[tid] = __fadd_rn(
            __fadd_rn(__fadd_rn(r[0], r[1]), __fadd_rn(r[2], r[3])),
            __fadd_rn(__fadd_rn(r[4], r[5]), __fadd_rn(r[6], r[7])));
    }
    // lds_sz visibility: barrier inside tile loop below

    float dbest[4] = {3.4e38f, 3.4e38f, 3.4e38f, 3.4e38f};
    int   kbest[4] = {0, 0, 0, 0};

    for (int t = 0; t < KC / KTILE; ++t) {
        // write prefetched tile -> et (scalar ds_writes, 2-way banks = free)
        #pragma unroll
        for (int q = 0; q < 8; ++q) {
            int cb = cq * 4 + q * 8;
            et[cb + 0][krow] = pf[q].x;
            et[cb + 1][krow] = pf[q].y;
            et[cb + 2][krow] = pf[q].z;
            et[cb + 3][krow] = pf[q].w;
        }
        // issue next tile's global loads now; they fly during compute
        if (t + 1 < KC / KTILE) {
            const float* er = emb + (size_t)((t + 1) * KTILE + krow) * 64 + cq * 4;
            #pragma unroll
            for (int q = 0; q < 8; ++q) pf[q] = *(const float4*)(er + q * 8);
        }
        __syncthreads();   // et (and lds_sz) ready

        float acc[4][8];
        #pragma unroll
        for (int i = 0; i < 4; ++i)
            #pragma unroll
            for (int j = 0; j < 8; ++j) acc[i][j] = 0.0f;

        #pragma unroll 8
        for (int c = 0; c < 64; ++c) {
            const float4 zv  = *(const float4*)&zt[c][tn * 4];
            const float4 ev0 = *(const float4*)&et[c][tk * 8];
            const float4 ev1 = *(const float4*)&et[c][tk * 8 + 4];
            const float zr[4] = {zv.x, zv.y, zv.z, zv.w};
            const float er[8] = {ev0.x, ev0.y, ev0.z, ev0.w,
                                 ev1.x, ev1.y, ev1.z, ev1.w};
            #pragma unroll
            for (int i = 0; i < 4; ++i)
                #pragma unroll
                for (int j = 0; j < 8; ++j)
                    acc[i][j] = __fmaf_rn(zr[i], er[j], acc[i][j]);
        }

        const int k0 = t * KTILE;
        const float4 sev0 = *(const float4*)(se + k0 + tk * 8);
        const float4 sev1 = *(const float4*)(se + k0 + tk * 8 + 4);
        const float ses[8] = {sev0.x, sev0.y, sev0.z, sev0.w,
                              sev1.x, sev1.y, sev1.z, sev1.w};
        const float4 szv = *(const float4*)&lds_sz[tn * 4];
        const float szs[4] = {szv.x, szv.y, szv.z, szv.w};

        #pragma unroll
        for (int i = 0; i < 4; ++i)
            #pragma unroll
            for (int j = 0; j < 8; ++j) {
                float s = __fadd_rn(szs[i], ses[j]);
                float d = __fmaf_rn(-2.0f, acc[i][j], s);   // == fsub(s, fmul(2,acc)) bitwise
                if (d < dbest[i]) { dbest[i] = d; kbest[i] = k0 + tk * 8 + j; }
            }
        __syncthreads();   // done reading et before next tile overwrites
    }

    #pragma unroll
    for (int i = 0; i < 4; ++i) {
        unsigned m = __float_as_uint(dbest[i]);
        m ^= ((int)m < 0) ? 0xFFFFFFFFu : 0x80000000u;
        atomicMin(&red[tn * 4 + i],
                  ((unsigned long long)m << 10) | (unsigned)kbest[i]);
    }
    __syncthreads();

    // ---- fused epilogue: idx, hist, z_q, sumsq (z slice already in zt) ----
    const int nl   = tid & 63;
    const int idxn = (int)(red[nl] & 1023ULL);
    if (tid < 64) {
        out[OUT_IDX + n0 + tid] = (float)idxn;
        atomicAdd(&hist[idxn], 1);
    }
    const float* erow  = emb + (size_t)idxn * 64;
    float*       obase = out + OUT_ZQ + (size_t)b * 65536 + hw0 + nl;
    const int c0 = tid >> 6;
    double s = 0.0;
    #pragma unroll
    for (int j = 0; j < 16; ++j) {
        int   c    = c0 + j * 4;
        float zv   = zt[c][nl];
        float ev   = erow[c];
        float diff = ev - zv;                       // z_q - z
        obase[(size_t)c * 1024] = zv + diff;        // straight-through
        s = fma((double)diff, (double)diff, s);
    }
    #pragma unroll
    for (int off = 32; off; off >>= 1) s += __shfl_down(s, off, 64);
    if ((tid & 63) == 0) atomicAdd(sumsq, s);
}

__global__ __launch_bounds__(256) void final_kernel(const int* __restrict__ hist,
                                                    const double* __restrict__ sumsq,
                                                    float* __restrict__ out) {
    __shared__ double red[256];
    const int tid = threadIdx.x;
    double s = 0.0;
    #pragma unroll
    for (int j = 0; j < 4; ++j) {
        int   kk = j * 256 + tid;
        float em = (float)hist[kk] * (1.0f / 65536.0f);
        float t  = em * logf(em + 1e-10f);
        s += (double)t;
    }
    red[tid] = s;
    __syncthreads();
    for (int off = 128; off > 0; off >>= 1) {
        if (tid < off) red[tid] += red[tid + off];
        __syncthreads();
    }
    if (tid == 0) {
        out[OUT_PPL] = expf(-(float)red[0]);
        out[0]       = 1.25f * (float)(sumsq[0] / 4194304.0);
    }
}

extern "C" void kernel_launch(void* const* d_in, const int* in_sizes, int n_in,
                              void* d_out, int out_size, void* d_ws, size_t ws_size,
                              hipStream_t stream) {
    const float* z   = (const float*)d_in[0];
    const float* emb = (const float*)d_in[1];
    float* out = (float*)d_out;
    char*  ws  = (char*)d_ws;

    int*    hist  = (int*)(ws + WS_HIST);
    double* sumsq = (double*)(ws + WS_SUMSQ);
    float*  se    = (float*)(ws + WS_SE);

    hipMemsetAsync(hist, 0, (size_t)KC * 4 + 8, stream);  // hist + sumsq contiguous

    prep_emb<<<KC / 256, 256, 0, stream>>>(emb, se);
    dist_fused<<<NVEC / NTILE, 256, 0, stream>>>(z, emb, se, out, hist, sumsq);
    final_kernel<<<1, 256, 0, stream>>>(hist, sumsq, out);
}

// Round 7
// 151.734 us; speedup vs baseline: 1.0016x; 1.0016x over previous
//
#include <hip/hip_runtime.h>

#define NVEC 65536   // B*H*W = 64*32*32
#define KC   1024
#define DD   64
#define NTILE 64     // n per block (lane = n)
#define KW   256     // k per wave (4 waves cover all 1024)
#define KU   32      // k-unroll (accs per lane)

// d_out layout (f32): [0]=loss, [1..4194305)=z_q (B,D,H,W), [4194305]=perplexity, [4194306..)=idx
#define OUT_ZQ   1
#define OUT_PPL  4194305
#define OUT_IDX  4194306

// ws layout (bytes)
#define WS_KEYS  0          // u64[NVEC]      = 524288
#define WS_HIST  524288     // int[KC]        = 4096
#define WS_SUMSQ 528384     // double         = 8
#define WS_SE    528392     // float[KC]      = 4096
#define WS_EMBT  532488     // float[DD*KC]   = 262144  (embT[c][k])

// prep: per 64 emb rows -> se[k] (numpy pairwise order, verified bit-exact)
// and embT[c][k] global transpose for contiguous-in-k scalar loads.
__global__ __launch_bounds__(256) void prep_kernel(const float* __restrict__ emb,
                                                   float* __restrict__ se,
                                                   float* __restrict__ embT) {
    __shared__ float tile[64][65];   // +1 pad
    const int tid = threadIdx.x;
    const int k0  = blockIdx.x * 64;

    // stage 64x64 tile: thread (r=tid>>2, q=tid&3) reads 4 float4
    {
        const int r = tid >> 2, q = tid & 3;
        const float* row = emb + (size_t)(k0 + r) * 64 + q * 16;
        #pragma unroll
        for (int i = 0; i < 4; ++i) {
            float4 v = *(const float4*)(row + i * 4);
            tile[r][q * 16 + i * 4 + 0] = v.x;
            tile[r][q * 16 + i * 4 + 1] = v.y;
            tile[r][q * 16 + i * 4 + 2] = v.z;
            tile[r][q * 16 + i * 4 + 3] = v.w;
        }
    }
    __syncthreads();

    if (tid < 64) {   // se: numpy pairwise (8 stride-8 accs, tree combine)
        float r[8];
        #pragma unroll
        for (int c = 0; c < 64; ++c) {
            float v = tile[tid][c];
            float s = __fmul_rn(v, v);
            if (c < 8) r[c] = s;
            else       r[c & 7] = __fadd_rn(r[c & 7], s);
        }
        se[k0 + tid] = __fadd_rn(
            __fadd_rn(__fadd_rn(r[0], r[1]), __fadd_rn(r[2], r[3])),
            __fadd_rn(__fadd_rn(r[4], r[5]), __fadd_rn(r[6], r[7])));
    }

    // transpose out: thread (kl=tid&63, cg=tid>>6) writes embT[c][k0+kl], c=cg*16..+15
    const int kl = tid & 63, cg = tid >> 6;
    #pragma unroll
    for (int i = 0; i < 16; ++i) {
        int c = cg * 16 + i;
        embT[(size_t)c * KC + k0 + kl] = tile[kl][c];
    }
}

// dist: block = 64 n x all 1024 k. lane = n; wave w owns k in [w*256, w*256+256).
// z-column in LDS (only per-lane LDS traffic); e comes from embT via wave-uniform
// scalar loads (SGPRs, scalar pipe) -> VALU-bound.
// Per (n,k): sequential __fmaf_rn over c=0..63 (single chain), then
// d = fmaf(-2, acc, fadd(sz, se)) -- bit-identical to verified chain.
// k ascending per wave + strict '<' => numpy first-index tie-break; cross-wave
// merge via (monotone<<10 | k) atomicMin in LDS.
__global__ __launch_bounds__(256)
void dist_kernel(const float* __restrict__ z,
                 const float* __restrict__ embT,
                 const float* __restrict__ se,
                 unsigned long long* __restrict__ keys) {
    __shared__ float zt[64][64];               // 16 KB [c][n]
    __shared__ float lds_sz[64];
    __shared__ unsigned long long red[64];

    const int tid  = threadIdx.x;
    const int lane = tid & 63;
    const int w    = tid >> 6;
    const int n0   = blockIdx.x * NTILE;
    const int b    = n0 >> 10;
    const int hw0  = n0 & 1023;

    // ---- stage zt[c][nl] (z is [b][c][hw]; hw n-contiguous) ----
    {
        const float* zbase = z + (size_t)b * 65536 + hw0;
        #pragma unroll
        for (int j = 0; j < 4; ++j) {
            int idx = tid + j * 256;
            int c   = idx >> 4;
            int nl4 = (idx & 15) * 4;
            *(float4*)&zt[c][nl4] = *(const float4*)(zbase + (size_t)c * 1024 + nl4);
        }
        if (tid < 64) red[tid] = 0xFFFFFFFFFFFFFFFFULL;
    }
    __syncthreads();

    // ---- sz[n]: numpy pairwise order from staged zt (verified) ----
    if (tid < 64) {
        float r[8];
        #pragma unroll
        for (int c = 0; c < 64; ++c) {
            float v = zt[c][tid];
            float s = __fmul_rn(v, v);
            if (c < 8) r[c] = s;
            else       r[c & 7] = __fadd_rn(r[c & 7], s);
        }
        lds_sz[tid] = __fadd_rn(
            __fadd_rn(__fadd_rn(r[0], r[1]), __fadd_rn(r[2], r[3])),
            __fadd_rn(__fadd_rn(r[4], r[5]), __fadd_rn(r[6], r[7])));
    }
    __syncthreads();

    const float szn = lds_sz[lane];
    const int   kb  = __builtin_amdgcn_readfirstlane(w * KW);  // provably uniform

    float dbest = 3.4e38f;
    int   kbestv = 0;

    for (int g = 0; g < KW; g += KU) {
        const int kg = kb + g;     // uniform
        float acc[KU];
        #pragma unroll
        for (int j = 0; j < KU; ++j) acc[j] = 0.0f;

        #pragma unroll 2
        for (int c = 0; c < 64; ++c) {
            const float zc = zt[c][lane];                       // per-lane LDS, conflict-free
            const float* __restrict__ eb = embT + (size_t)c * KC + kg;  // uniform -> s_load
            #pragma unroll
            for (int j = 0; j < KU; ++j)
                acc[j] = __fmaf_rn(zc, eb[j], acc[j]);
        }

        const float* __restrict__ sb = se + kg;                 // uniform
        #pragma unroll
        for (int j = 0; j < KU; ++j) {
            float d = __fmaf_rn(-2.0f, acc[j], __fadd_rn(szn, sb[j]));
            if (d < dbest) { dbest = d; kbestv = kg + j; }      // ascending k, strict <
        }
    }

    unsigned m = __float_as_uint(dbest);
    m ^= ((int)m < 0) ? 0xFFFFFFFFu : 0x80000000u;
    atomicMin(&red[lane], ((unsigned long long)m << 10) | (unsigned)kbestv);
    __syncthreads();
    if (tid < 64) keys[n0 + tid] = red[tid];
}

__global__ __launch_bounds__(256) void epilogue_kernel(const float* __restrict__ z,
                                                       const float* __restrict__ emb,
                                                       const unsigned long long* __restrict__ keys,
                                                       float* __restrict__ out,
                                                       int* __restrict__ hist,
                                                       double* __restrict__ sumsq) {
    __shared__ double red[256];
    const int tid = threadIdx.x;
    const int n   = blockIdx.x * 256 + tid;
    const int b   = n >> 10;
    const int hw  = n & 1023;
    const int idx = (int)(keys[n] & 1023ULL);

    out[OUT_IDX + n] = (float)idx;
    atomicAdd(&hist[idx], 1);

    const float* zp = z   + (size_t)b * 65536 + hw;
    float*       op = out + OUT_ZQ + (size_t)b * 65536 + hw;
    const float* er = emb + (size_t)idx * DD;
    double s = 0.0;
    #pragma unroll
    for (int c = 0; c < DD; ++c) {
        float zv   = zp[(size_t)c * 1024];
        float ev   = er[c];
        float diff = ev - zv;                  // z_q - z
        op[(size_t)c * 1024] = zv + diff;      // straight-through
        s = fma((double)diff, (double)diff, s);
    }
    red[tid] = s;
    __syncthreads();
    for (int off = 128; off > 0; off >>= 1) {
        if (tid < off) red[tid] += red[tid + off];
        __syncthreads();
    }
    if (tid == 0) atomicAdd(sumsq, red[0]);
}

__global__ __launch_bounds__(256) void final_kernel(const int* __restrict__ hist,
                                                    const double* __restrict__ sumsq,
                                                    float* __restrict__ out) {
    __shared__ double red[256];
    const int tid = threadIdx.x;
    double s = 0.0;
    #pragma unroll
    for (int j = 0; j < 4; ++j) {
        int   kk = j * 256 + tid;
        float em = (float)hist[kk] * (1.0f / 65536.0f);
        float t  = em * logf(em + 1e-10f);
        s += (double)t;
    }
    red[tid] = s;
    __syncthreads();
    for (int off = 128; off > 0; off >>= 1) {
        if (tid < off) red[tid] += red[tid + off];
        __syncthreads();
    }
    if (tid == 0) {
        out[OUT_PPL] = expf(-(float)red[0]);
        out[0]       = 1.25f * (float)(sumsq[0] / 4194304.0);
    }
}

extern "C" void kernel_launch(void* const* d_in, const int* in_sizes, int n_in,
                              void* d_out, int out_size, void* d_ws, size_t ws_size,
                              hipStream_t stream) {
    const float* z   = (const float*)d_in[0];
    const float* emb = (const float*)d_in[1];
    float* out = (float*)d_out;
    char*  ws  = (char*)d_ws;

    unsigned long long* keys  = (unsigned long long*)(ws + WS_KEYS);
    int*                hist  = (int*)(ws + WS_HIST);
    double*             sumsq = (double*)(ws + WS_SUMSQ);
    float*              se    = (float*)(ws + WS_SE);
    float*              embT  = (float*)(ws + WS_EMBT);

    hipMemsetAsync(hist, 0, (size_t)KC * 4 + 8, stream);  // hist + sumsq contiguous

    prep_kernel<<<KC / 64, 256, 0, stream>>>(emb, se, embT);
    dist_kernel<<<NVEC / NTILE, 256, 0, stream>>>(z, embT, se, keys);
    epilogue_kernel<<<NVEC / 256, 256, 0, stream>>>(z, emb, keys, out, hist, sumsq);
    final_kernel<<<1, 256, 0, stream>>>(hist, sumsq, out);
}